// Round 1
// baseline (366.895 us; speedup 1.0000x reference)
//
#include <hip/hip_runtime.h>

// ---------------------------------------------------------------------------
// DeformableTransformerEncoderLayer on MI355X (gfx950)
// Pipeline:
//   prep:   qb = bf16(src+pos), srcb = bf16(src)            (padded to M_pad)
//   GEMM:   off  = qb @ W_off  + b_off        (f32 out)
//   GEMM:   attn = qb @ W_attn + b_attn       (f32 out)
//   GEMM:   valb = srcb @ W_val + b_val       (bf16 out)
//   sample: outb = MSDeformAttn(off, softmax(attn), valb)   (bf16 out)
//   GEMM:   src2 = outb @ W_out + b_out       (f32 out)
//   LN1:    x = LN(src+src2)*g1+beta1  -> x (f32), xb (bf16, padded 0)
//   GEMM:   hb  = relu(xb @ W1 + b1)          (bf16 out)
//   GEMM:   f2  = hb @ W2 + b2                (f32 out)
//   LN2:    d_out = LN(x+f2)*g2+beta2
// All GEMMs: bf16 inputs, fp32 accumulate via v_mfma_f32_16x16x32_bf16.
// ---------------------------------------------------------------------------

typedef __bf16 bf16x8 __attribute__((ext_vector_type(8)));
typedef float floatx4 __attribute__((ext_vector_type(4)));

#define S_TOTAL 13294
#define M_ROWS  26588      // 2 * 13294
#define M_PAD   26624      // 208 * 128
#define DMODEL  256

// ---------------- weight convert: W (K x N) f32 -> WT (N x K) bf16 ----------
__global__ __launch_bounds__(256) void convert_wt(const float* __restrict__ W,
                                                  __bf16* __restrict__ WT,
                                                  int K, int N) {
    int i = blockIdx.x * 256 + threadIdx.x;
    if (i >= N * K) return;
    int n = i / K, k = i - n * K;
    WT[i] = (__bf16)W[(size_t)k * N + n];
}

// ---------------- prep: qb = bf16(src+pos), srcb = bf16(src), zero-pad ------
__global__ __launch_bounds__(256) void prep_k(const float* __restrict__ src,
                                              const float* __restrict__ pos,
                                              __bf16* __restrict__ qb,
                                              __bf16* __restrict__ srcb) {
    int i = blockIdx.x * 256 + threadIdx.x;   // over M_PAD*256
    if (i < M_ROWS * DMODEL) {
        float s = src[i];
        qb[i]   = (__bf16)(s + pos[i]);
        srcb[i] = (__bf16)s;
    } else {
        qb[i]   = (__bf16)0.f;
        srcb[i] = (__bf16)0.f;
    }
}

// ---------------- 128x128 tile bf16 MFMA GEMM ------------------------------
// A: (M_PAD x K) bf16 row-major.  BT: (N x K) bf16 row-major (i.e. B^T).
// C = A@B + bias, optional relu, f32 or bf16 output.
template <bool RELU, bool BF16OUT>
__global__ __launch_bounds__(256, 2) void gemm128(const __bf16* __restrict__ A,
                                                  const __bf16* __restrict__ BT,
                                                  const float* __restrict__ bias,
                                                  float* __restrict__ Cf,
                                                  __bf16* __restrict__ Cb,
                                                  int N, int K) {
    __shared__ __align__(16) __bf16 As[128][40];   // +8 pad: bank-conflict break
    __shared__ __align__(16) __bf16 Bs[128][40];   // Bs[n][k]
    const int tid  = threadIdx.x;
    const int bm   = blockIdx.y, bn = blockIdx.x;
    const int wave = tid >> 6, lane = tid & 63;
    const int wr   = wave >> 1, wc = wave & 1;
    const int l16  = lane & 15, quad = lane >> 4;

    floatx4 acc[4][4] = {};

    const __bf16* Ag = A  + (size_t)(bm * 128 + (tid >> 1)) * K + (tid & 1) * 16;
    const __bf16* Bg = BT + (size_t)(bn * 128 + (tid >> 1)) * K + (tid & 1) * 16;
    __bf16* arow = &As[tid >> 1][(tid & 1) * 16];
    __bf16* brow = &Bs[tid >> 1][(tid & 1) * 16];

    for (int k0 = 0; k0 < K; k0 += 32) {
        uint4 a0 = *(const uint4*)(Ag + k0);
        uint4 a1 = *(const uint4*)(Ag + k0 + 8);
        uint4 b0 = *(const uint4*)(Bg + k0);
        uint4 b1 = *(const uint4*)(Bg + k0 + 8);
        __syncthreads();                 // prior iter's LDS reads done
        *(uint4*)arow       = a0;
        *(uint4*)(arow + 8) = a1;
        *(uint4*)brow       = b0;
        *(uint4*)(brow + 8) = b1;
        __syncthreads();
        bf16x8 af[4], bf[4];
#pragma unroll
        for (int i = 0; i < 4; i++)
            af[i] = *(const bf16x8*)&As[wr * 64 + i * 16 + l16][quad * 8];
#pragma unroll
        for (int j = 0; j < 4; j++)
            bf[j] = *(const bf16x8*)&Bs[wc * 64 + j * 16 + l16][quad * 8];
#pragma unroll
        for (int i = 0; i < 4; i++)
#pragma unroll
            for (int j = 0; j < 4; j++)
                acc[i][j] = __builtin_amdgcn_mfma_f32_16x16x32_bf16(
                    af[i], bf[j], acc[i][j], 0, 0, 0);
    }

    const int row0 = bm * 128 + wr * 64;
    const int col0 = bn * 128 + wc * 64;
#pragma unroll
    for (int j = 0; j < 4; j++) {
        int   n  = col0 + j * 16 + l16;
        float bv = bias[n];
#pragma unroll
        for (int i = 0; i < 4; i++) {
            int m = row0 + i * 16 + quad * 4;
#pragma unroll
            for (int r = 0; r < 4; r++) {
                float v = acc[i][j][r] + bv;
                if (RELU) v = v > 0.f ? v : 0.f;
                if (BF16OUT) Cb[(size_t)(m + r) * N + n] = (__bf16)v;
                else         Cf[(size_t)(m + r) * N + n] = v;
            }
        }
    }
}

// ---------------- MSDeformAttn sampling ------------------------------------
// one block per padded row r; 8 heads x 4 levels x 4 points
__global__ __launch_bounds__(256) void sample_k(const float* __restrict__ offb,
                                                const float* __restrict__ attnb,
                                                const __bf16* __restrict__ valb,
                                                const float* __restrict__ refp,
                                                __bf16* __restrict__ outb) {
    const int r   = blockIdx.x;
    const int tid = threadIdx.x;
    if (r >= M_ROWS) {                       // zero the padded rows
        outb[(size_t)r * 256 + tid] = (__bf16)0.f;
        return;
    }
    __shared__ float s_log[128];
    __shared__ int   s_row[128][4];
    __shared__ float s_w[128][4];

    const int n = (r >= S_TOTAL) ? 1 : 0;

    if (tid < 128) s_log[tid] = attnb[(size_t)r * 128 + tid];
    __syncthreads();

    if (tid < 128) {
        const int HL[4] = {100, 50, 25, 13};
        const int ST[4] = {0, 10000, 12500, 13125};
        int h = tid >> 4, lp = tid & 15, l = lp >> 2;
        float mx = -1e30f;
        for (int i = 0; i < 16; i++) mx = fmaxf(mx, s_log[h * 16 + i]);
        float sum = 0.f;
        for (int i = 0; i < 16; i++) sum += __expf(s_log[h * 16 + i] - mx);
        float aw = __expf(s_log[tid] - mx) / sum;

        float ox = offb[(size_t)r * 256 + tid * 2];
        float oy = offb[(size_t)r * 256 + tid * 2 + 1];
        float rx = refp[((size_t)r * 4 + l) * 2];
        float ry = refp[((size_t)r * 4 + l) * 2 + 1];
        int   Wl = HL[l], Hl = HL[l];
        // x = (rx + ox/Wl)*Wl - 0.5 == rx*Wl + ox - 0.5
        float x = rx * (float)Wl + ox - 0.5f;
        float y = ry * (float)Hl + oy - 0.5f;
        float xf = floorf(x), yf = floorf(y);
        float wx1 = x - xf, wy1 = y - yf;
        float wx0 = 1.f - wx1, wy0 = 1.f - wy1;
        int x0 = (int)xf, y0 = (int)yf;
        int base = n * S_TOTAL + ST[l];
#pragma unroll
        for (int c = 0; c < 4; c++) {
            int yy = y0 + (c >> 1), xx = x0 + (c & 1);
            bool valid = (yy >= 0) & (yy < Hl) & (xx >= 0) & (xx < Wl);
            int yc = min(max(yy, 0), Hl - 1);
            int xc = min(max(xx, 0), Wl - 1);
            float w = ((c >> 1) ? wy1 : wy0) * ((c & 1) ? wx1 : wx0);
            s_row[tid][c] = base + yc * Wl + xc;
            s_w[tid][c]   = valid ? w * aw : 0.f;
        }
    }
    __syncthreads();

    const int h = tid >> 5, ch = tid & 31;
    const __bf16* vb = valb + h * 32 + ch;
    float acc = 0.f;
#pragma unroll 4
    for (int lp = 0; lp < 16; lp++) {
        int idx = h * 16 + lp;
#pragma unroll
        for (int c = 0; c < 4; c++) {
            float w  = s_w[idx][c];
            int   rr = s_row[idx][c];
            acc += w * (float)vb[(size_t)rr * 256];
        }
    }
    outb[(size_t)r * 256 + tid] = (__bf16)acc;
}

// ---------------- LayerNorm kernels ----------------------------------------
// LN1: x = LN(src + src2), store f32 x and bf16 xb (zero-padded rows)
__global__ __launch_bounds__(64) void ln1_k(const float* __restrict__ src,
                                            const float* __restrict__ src2,
                                            const float* __restrict__ g,
                                            const float* __restrict__ b,
                                            float* __restrict__ x,
                                            __bf16* __restrict__ xb) {
    const int r = blockIdx.x, lane = threadIdx.x;
    if (r >= M_ROWS) {
#pragma unroll
        for (int j = 0; j < 4; j++) xb[(size_t)r * 256 + lane * 4 + j] = (__bf16)0.f;
        return;
    }
    size_t base = (size_t)r * 256 + lane * 4;
    float4 a = *(const float4*)(src + base);
    float4 c = *(const float4*)(src2 + base);
    float v0 = a.x + c.x, v1 = a.y + c.y, v2 = a.z + c.z, v3 = a.w + c.w;
    float s  = v0 + v1 + v2 + v3;
    float sq = v0 * v0 + v1 * v1 + v2 * v2 + v3 * v3;
    for (int o = 32; o > 0; o >>= 1) {
        s  += __shfl_xor(s, o);
        sq += __shfl_xor(sq, o);
    }
    float mean = s * (1.f / 256.f);
    float var  = sq * (1.f / 256.f) - mean * mean;
    float rs   = rsqrtf(var + 1e-5f);
    float4 gg = *(const float4*)(g + lane * 4);
    float4 bb = *(const float4*)(b + lane * 4);
    float o0 = (v0 - mean) * rs * gg.x + bb.x;
    float o1 = (v1 - mean) * rs * gg.y + bb.y;
    float o2 = (v2 - mean) * rs * gg.z + bb.z;
    float o3 = (v3 - mean) * rs * gg.w + bb.w;
    *(float4*)(x + base) = make_float4(o0, o1, o2, o3);
    xb[base]     = (__bf16)o0;
    xb[base + 1] = (__bf16)o1;
    xb[base + 2] = (__bf16)o2;
    xb[base + 3] = (__bf16)o3;
}

// LN2: out = LN(x + f2)  (f32 output, valid rows only)
__global__ __launch_bounds__(64) void ln2_k(const float* __restrict__ x,
                                            const float* __restrict__ f2,
                                            const float* __restrict__ g,
                                            const float* __restrict__ b,
                                            float* __restrict__ out) {
    const int r = blockIdx.x, lane = threadIdx.x;
    size_t base = (size_t)r * 256 + lane * 4;
    float4 a = *(const float4*)(x + base);
    float4 c = *(const float4*)(f2 + base);
    float v0 = a.x + c.x, v1 = a.y + c.y, v2 = a.z + c.z, v3 = a.w + c.w;
    float s  = v0 + v1 + v2 + v3;
    float sq = v0 * v0 + v1 * v1 + v2 * v2 + v3 * v3;
    for (int o = 32; o > 0; o >>= 1) {
        s  += __shfl_xor(s, o);
        sq += __shfl_xor(sq, o);
    }
    float mean = s * (1.f / 256.f);
    float var  = sq * (1.f / 256.f) - mean * mean;
    float rs   = rsqrtf(var + 1e-5f);
    float4 gg = *(const float4*)(g + lane * 4);
    float4 bb = *(const float4*)(b + lane * 4);
    float4 o4;
    o4.x = (v0 - mean) * rs * gg.x + bb.x;
    o4.y = (v1 - mean) * rs * gg.y + bb.y;
    o4.z = (v2 - mean) * rs * gg.z + bb.z;
    o4.w = (v3 - mean) * rs * gg.w + bb.w;
    *(float4*)(out + base) = o4;
}

// ---------------------------------------------------------------------------
extern "C" void kernel_launch(void* const* d_in, const int* in_sizes, int n_in,
                              void* d_out, int out_size, void* d_ws, size_t ws_size,
                              hipStream_t stream) {
    const float* src  = (const float*)d_in[0];
    const float* pos  = (const float*)d_in[1];
    const float* refp = (const float*)d_in[2];
    // d_in[3], d_in[4]: static metadata (hard-coded)
    const float* W_off  = (const float*)d_in[5];
    const float* b_off  = (const float*)d_in[6];
    const float* W_attn = (const float*)d_in[7];
    const float* b_attn = (const float*)d_in[8];
    const float* W_val  = (const float*)d_in[9];
    const float* b_val  = (const float*)d_in[10];
    const float* W_out  = (const float*)d_in[11];
    const float* b_out  = (const float*)d_in[12];
    const float* W1     = (const float*)d_in[13];
    const float* b1     = (const float*)d_in[14];
    const float* W2     = (const float*)d_in[15];
    const float* b2     = (const float*)d_in[16];
    const float* g1     = (const float*)d_in[17];
    const float* beta1  = (const float*)d_in[18];
    const float* g2     = (const float*)d_in[19];
    const float* beta2  = (const float*)d_in[20];
    float* out = (float*)d_out;

    // ---- workspace layout (regions aliased across pipeline stages) --------
    const size_t R256B = (size_t)M_PAD * 256 * 2;  // 13,631,488 (bf16 row256)
    const size_t R256F = (size_t)M_PAD * 256 * 4;  // 27,262,976 (f32  row256)
    char* ws = (char*)d_ws;
    char* regA = ws;                    // 13.6 MB
    char* regB = ws + R256B;            // 13.6 MB
    char* regC = ws + 2 * R256B;        // 27.3 MB
    char* regD = ws + 2 * R256B + R256F;            // 13.6 MB
    char* regE = regD + R256B;                      // 13.6 MB
    char* regF = regE + R256B;                      // 27.3 MB
    char* regW = regF + R256F;                      // weights ~1.5 MB

    __bf16* qb    = (__bf16*)regA;
    __bf16* srcb  = (__bf16*)regB;
    float*  offf  = (float*)regC;
    float*  attnf = (float*)regD;
    __bf16* valb  = (__bf16*)regE;
    __bf16* outb  = (__bf16*)regA;      // reuse qb after attn/off GEMMs
    float*  src2  = (float*)regC;       // reuse off after sampling
    float*  x     = (float*)regF;
    __bf16* xb    = (__bf16*)regE;      // reuse valb after sampling
    __bf16* hb    = (__bf16*)regA;      // spans A+B+C (54.5 MB) for M_PAD x 1024
    float*  f2    = (float*)regD;       // spans D+E (27.3 MB)

    __bf16* WToff  = (__bf16*)(regW);
    __bf16* WTattn = (__bf16*)(regW + 131072);
    __bf16* WTval  = (__bf16*)(regW + 196608);
    __bf16* WTout  = (__bf16*)(regW + 327680);
    __bf16* WT1    = (__bf16*)(regW + 458752);
    __bf16* WT2    = (__bf16*)(regW + 983040);

    // ---- weight conversion (f32 KxN -> bf16 NxK) --------------------------
    auto cvt = [&](const float* W, __bf16* WT, int K, int N) {
        convert_wt<<<(N * K + 255) / 256, 256, 0, stream>>>(W, WT, K, N);
    };
    cvt(W_off, WToff, 256, 256);
    cvt(W_attn, WTattn, 256, 128);
    cvt(W_val, WTval, 256, 256);
    cvt(W_out, WTout, 256, 256);
    cvt(W1, WT1, 256, 1024);
    cvt(W2, WT2, 1024, 256);

    // ---- prep -------------------------------------------------------------
    prep_k<<<M_PAD, 256, 0, stream>>>(src, pos, qb, srcb);

    // ---- projections ------------------------------------------------------
    gemm128<false, false><<<dim3(2, M_PAD / 128), 256, 0, stream>>>(
        qb, WToff, b_off, offf, nullptr, 256, 256);
    gemm128<false, false><<<dim3(1, M_PAD / 128), 256, 0, stream>>>(
        qb, WTattn, b_attn, attnf, nullptr, 128, 256);
    gemm128<false, true><<<dim3(2, M_PAD / 128), 256, 0, stream>>>(
        srcb, WTval, b_val, nullptr, valb, 256, 256);

    // ---- deformable sampling ---------------------------------------------
    sample_k<<<M_PAD, 256, 0, stream>>>(offf, attnf, valb, refp, outb);

    // ---- output projection + LN1 -----------------------------------------
    gemm128<false, false><<<dim3(2, M_PAD / 128), 256, 0, stream>>>(
        outb, WTout, b_out, src2, nullptr, 256, 256);
    ln1_k<<<M_PAD, 64, 0, stream>>>(src, src2, g1, beta1, x, xb);

    // ---- FFN + LN2 --------------------------------------------------------
    gemm128<true, true><<<dim3(8, M_PAD / 128), 256, 0, stream>>>(
        xb, WT1, b1, nullptr, hb, 1024, 256);
    gemm128<false, false><<<dim3(2, M_PAD / 128), 256, 0, stream>>>(
        hb, WT2, b2, f2, nullptr, 256, 1024);
    ln2_k<<<M_ROWS, 64, 0, stream>>>(x, f2, g2, beta2, out);
}